// Round 2
// baseline (304.161 us; speedup 1.0000x reference)
//
#include <hip/hip_runtime.h>
#include <hip/hip_bf16.h>

#define N_NODES 6144
#define IN_F 256
#define N_HEADS 4
#define N_HID 64
#define JS 8
#define JLEN (N_NODES / JS)        // 768
#define NW (JLEN / 32)             // 24 u32 mask words per chunk row
#define SM_STRIDE 25               // u32 words/row in LDS; 25 coprime 32 -> conflict-free
#define PACK_BLOCKS 768            // adj-pack blocks fused into prep kernel
#define ACC_F32 (N_HEADS * N_NODES * N_HID + N_HEADS * N_NODES)  // 1,597,440 f32
#define ZERO_F4_PER_BLOCK 520      // ACC_F32 / PACK_BLOCKS / 4 == 520 exactly

typedef __attribute__((ext_vector_type(4))) float floatx4;
typedef _Float16 half2_t __attribute__((ext_vector_type(2)));
typedef _Float16 half8_t __attribute__((ext_vector_type(8)));
typedef __attribute__((ext_vector_type(4))) unsigned uint4_t;
typedef short short2v __attribute__((ext_vector_type(2)));

__device__ __forceinline__ void atomAddF32(float* p, float v) {
    unsafeAtomicAdd(p, v);   // global_atomic_add_f32; ws is coarse-grained device mem
}

// ---------------- Kernel 1 (fused): blocks [0,768) pack adj -> 64-bit ballot masks
// (HBM-bound) and zero the accumulators; blocks [768,1536) do ht = h @ W fp32
// (VALU/LDS-bound). The two phases overlap on different pipes.
// gmask layout: u64 word (jc*6144 + r)*12 + wl covers j = jc*768 + wl*64 + bit.
__global__ __launch_bounds__(256) void prep_kernel(
    const float* __restrict__ h, const float* __restrict__ W,
    const float* __restrict__ a, const int* __restrict__ adj,
    short* __restrict__ htF, float* __restrict__ srcv,
    unsigned* __restrict__ tE1pk, unsigned* __restrict__ tE2pk,
    unsigned long long* __restrict__ gmask, float* __restrict__ accZero)
{
    __shared__ float As[32][34];
    __shared__ float Bs[32][68];
    __shared__ float redS[32][16];
    __shared__ float redT[32][16];
    __shared__ unsigned short eh1[32], eh2[32];

    if (blockIdx.x < PACK_BLOCKS) {
        // zero this block's slice of the accumulator region (520 float4)
        {
            float4* z = (float4*)accZero + (size_t)blockIdx.x * ZERO_F4_PER_BLOCK;
            const float4 zv = {0.f, 0.f, 0.f, 0.f};
            for (int i = threadIdx.x; i < ZERO_F4_PER_BLOCK; i += 256) z[i] = zv;
        }
        // ---- adjacency ballot-pack: 192 u64 words per wave, 16-way unrolled
        const int lane = threadIdx.x & 63;
        const int wave = threadIdx.x >> 6;
        const int wbase = (blockIdx.x * 4 + wave) * 192;
        for (int k0 = 0; k0 < 192; k0 += 16) {
            int v[16];
            #pragma unroll
            for (int s = 0; s < 16; ++s) {
                const int widx = wbase + k0 + s;
                const int r = widx / 96, c = widx % 96;     // row, 64-col group
                v[s] = adj[(size_t)r * N_NODES + c * 64 + lane];
            }
            #pragma unroll
            for (int s = 0; s < 16; ++s) {
                const unsigned long long b = __ballot(v[s] > 0);
                const int widx = wbase + k0 + s;
                const int r = widx / 96, c = widx % 96;
                const int jcp = c / 12, wl = c % 12;
                if (lane == 0)
                    gmask[((size_t)jcp * N_NODES + r) * 12 + wl] = b;
            }
        }
        return;
    }

    // ---- ht GEMM (unchanged math; flattened block index)
    const int gbx = blockIdx.x - PACK_BLOCKS;
    const int head = gbx & 3;
    const int i0 = (gbx >> 2) * 32;
    const int tid = threadIdx.x;
    const int tx = tid & 15, ty = tid >> 4;

    float acc[2][4] = {};

    for (int k0 = 0; k0 < IN_F; k0 += 32) {
        __syncthreads();
        {
            const int m = tid >> 3, kq = tid & 7;
            const float4 v = *(const float4*)(h + (i0 + m) * IN_F + k0 + kq * 4);
            As[kq*4+0][m] = v.x; As[kq*4+1][m] = v.y;
            As[kq*4+2][m] = v.z; As[kq*4+3][m] = v.w;
        }
        #pragma unroll
        for (int it = 0; it < 2; ++it) {
            int l = it * 256 + tid;
            int k = l >> 4, nq = l & 15;
            *(float4*)&Bs[k][nq*4] = *(const float4*)(W + (k0 + k) * 256 + head * 64 + nq * 4);
        }
        __syncthreads();
        #pragma unroll
        for (int kk = 0; kk < 32; ++kk) {
            const float2 av = *(const float2*)&As[kk][ty*2];
            const float4 bv = *(const float4*)&Bs[kk][tx*4];
            const float aa[2] = {av.x, av.y};
            const float bb[4] = {bv.x, bv.y, bv.z, bv.w};
            #pragma unroll
            for (int r = 0; r < 2; ++r)
                #pragma unroll
                for (int c = 0; c < 4; ++c)
                    acc[r][c] = fmaf(aa[r], bb[c], acc[r][c]);
        }
    }

    #pragma unroll
    for (int r = 0; r < 2; ++r)
        #pragma unroll
        for (int c2 = 0; c2 < 4; ++c2) {
            const int d = tx * 4 + c2;
            const int j = i0 + ty * 2 + r;
            const int jt = j >> 5, q = (j >> 3) & 3, u = j & 7;
            const int c = d >> 4, n = d & 15;
            const size_t F = (((((size_t)head * 192 + jt) * 4 + c) * 16 + n) * 4 + q) * 8 + u;
            const _Float16 hv = (_Float16)acc[r][c2];
            htF[F] = *(const short*)&hv;
        }

    float as_[4], at_[4];
    #pragma unroll
    for (int c = 0; c < 4; ++c) {
        as_[c] = a[head * 128 + tx * 4 + c];
        at_[c] = a[head * 128 + 64 + tx * 4 + c];
    }
    #pragma unroll
    for (int r = 0; r < 2; ++r) {
        float ps = 0.f, pt = 0.f;
        #pragma unroll
        for (int c = 0; c < 4; ++c) {
            ps = fmaf(acc[r][c], as_[c], ps);
            pt = fmaf(acc[r][c], at_[c], pt);
        }
        redS[ty*2+r][tx] = ps;
        redT[ty*2+r][tx] = pt;
    }
    __syncthreads();
    if (tid < 64) {
        const int row = tid & 31;
        const float* src = (tid < 32) ? &redS[row][0] : &redT[row][0];
        float s = 0.f;
        #pragma unroll
        for (int x = 0; x < 16; ++x) s += src[x];
        if (tid < 32) {
            srcv[head * N_NODES + i0 + row] = s;
        } else {
            const _Float16 E1 = (_Float16)__expf(s);
            const _Float16 E2 = (_Float16)__expf(0.2f * s);
            eh1[row] = *(const unsigned short*)&E1;
            eh2[row] = *(const unsigned short*)&E2;
        }
    }
    __syncthreads();
    if (tid < 16) {
        const unsigned v1 = (unsigned)eh1[2*tid] | ((unsigned)eh1[2*tid+1] << 16);
        const unsigned v2 = (unsigned)eh2[2*tid] | ((unsigned)eh2[2*tid+1] << 16);
        tE1pk[head * (N_NODES/2) + i0/2 + tid] = v1;
        tE2pk[head * (N_NODES/2) + i0/2 + tid] = v2;
    }
}

// ---------------- Kernel 2: masked softmax + PV. 32 rows/block -> grid 1536
// (6 blocks/CU offered vs 3 before). Mask read from packed global (3 KB/block,
// contiguous); E1/E2 prefetched from L2-resident global tables. LDS: 3.2 KB.
// Epilogue accumulates into per-head accN/accD via f32 HW atomics (8 adds/cell).
__global__ __launch_bounds__(256, 4) void gat_main_kernel(
    const unsigned* __restrict__ gmask32, const short* __restrict__ htF,
    const float* __restrict__ srcv, const unsigned* __restrict__ tE1pk,
    const unsigned* __restrict__ tE2pk,
    float* __restrict__ accNg, float* __restrict__ accDg)
{
    __shared__ unsigned smask[32 * SM_STRIDE];   // 3.2 KB

    const int bid = blockIdx.x;
    const int xcd = bid & 7;
    const int idx = bid >> 3;
    const int jc = idx / 24;                      // 8 j-chunks
    const int rb0 = ((idx % 24) * 8 + xcd) * 32;  // 192 row-blocks of 32

    const int lane = threadIdx.x;
    const int head = threadIdx.y;                 // wave = head
    const int m = lane & 15, quad = lane >> 4;
    const int jbase = jc * JLEN;
    const int tid = head * 64 + lane;

    // ---- stage this block's 32x768-bit mask tile: 768 u32, contiguous in global
    {
        const unsigned* g = gmask32 + ((size_t)jc * N_NODES + rb0) * 24;
        #pragma unroll
        for (int it = 0; it < 3; ++it) {
            const int f = it * 256 + tid;         // 0..767
            smask[(f / 24) * SM_STRIDE + (f % 24)] = g[f];
        }
    }
    __syncthreads();

    half2_t e1s[2], e2s[2];
    #pragma unroll
    for (int t = 0; t < 2; ++t) {
        const float sv = srcv[head * N_NODES + rb0 + t * 16 + m];
        const _Float16 a1 = (_Float16)__expf(sv);
        const _Float16 a2 = (_Float16)__expf(0.2f * sv);
        e1s[t] = (half2_t){a1, a1};
        e2s[t] = (half2_t){a2, a2};
    }

    const short* fb = htF + ((size_t)(head * 192 + (jbase >> 5)) * 4) * 512 + (m * 4 + quad) * 8;
    const unsigned* pe1 = tE1pk + head * (N_NODES/2) + (jbase >> 1) + quad * 4;
    const unsigned* pe2 = tE2pk + head * (N_NODES/2) + (jbase >> 1) + quad * 4;

    half8_t bones;
    #pragma unroll
    for (int u = 0; u < 8; ++u) bones[u] = (_Float16)1.0f;

    floatx4 accN[2][4];
    floatx4 accD[2];
    #pragma unroll
    for (int t = 0; t < 2; ++t) {
        accD[t] = (floatx4){0,0,0,0};
        #pragma unroll
        for (int c = 0; c < 4; ++c) accN[t][c] = (floatx4){0,0,0,0};
    }

    // depth-1 prefetch of B-fragments and E words
    half8_t bn[4];
    #pragma unroll
    for (int c = 0; c < 4; ++c) bn[c] = *(const half8_t*)(fb + c * 512);
    uint4_t E1n = *(const uint4_t*)pe1;
    uint4_t E2n = *(const uint4_t*)pe2;

    for (int w = 0; w < NW; ++w) {
        half8_t bc[4];
        #pragma unroll
        for (int c = 0; c < 4; ++c) bc[c] = bn[c];
        const uint4_t E1 = E1n, E2 = E2n;

        const int wn = (w + 1 < NW) ? (w + 1) : w;      // clamped prefetch
        #pragma unroll
        for (int c = 0; c < 4; ++c)
            bn[c] = *(const half8_t*)(fb + (size_t)wn * 2048 + c * 512);
        E1n = *(const uint4_t*)(pe1 + wn * 16);
        E2n = *(const uint4_t*)(pe2 + wn * 16);

        const unsigned E1a[4] = {E1.x, E1.y, E1.z, E1.w};
        const unsigned E2a[4] = {E2.x, E2.y, E2.z, E2.w};

        #pragma unroll
        for (int t = 0; t < 2; ++t) {
            const unsigned bits = (smask[(t * 16 + m) * SM_STRIDE + w] >> (quad * 8)) & 0xffu;
            const short2v tt = __builtin_bit_cast(short2v, bits * 0x10001u);
            uint4_t af_u;
            #pragma unroll
            for (int p = 0; p < 4; ++p) {
                const short2v shl = (p == 0) ? (short2v){15,14} : (p == 1) ? (short2v){13,12}
                                 : (p == 2) ? (short2v){11,10} : (short2v){9,8};
                const short2v k = (tt << shl) >> (short2v){15,15};   // 0xFFFF/0x0000 per half
                const half2_t p1 = __builtin_bit_cast(half2_t, E1a[p]) * e1s[t];
                const half2_t p2 = __builtin_bit_cast(half2_t, E2a[p]) * e2s[t];
                const half2_t mx = __builtin_elementwise_max(p1, p2); // exp(lrelu) = max of exps
                const unsigned r = __builtin_bit_cast(unsigned, mx) & __builtin_bit_cast(unsigned, k);
                if (p == 0) af_u.x = r; else if (p == 1) af_u.y = r;
                else if (p == 2) af_u.z = r; else af_u.w = r;
            }
            const half8_t af = __builtin_bit_cast(half8_t, af_u);
            #pragma unroll
            for (int c = 0; c < 4; ++c)
                accN[t][c] = __builtin_amdgcn_mfma_f32_16x16x32_f16(af, bc[c], accN[t][c], 0, 0, 0);
            accD[t] = __builtin_amdgcn_mfma_f32_16x16x32_f16(af, bones, accD[t], 0, 0, 0);
        }
    }

    const size_t nb = (size_t)head * N_NODES;
    #pragma unroll
    for (int t = 0; t < 2; ++t) {
        #pragma unroll
        for (int r = 0; r < 4; ++r) {
            const int gi = rb0 + t * 16 + quad * 4 + r;
            if (m == 0) atomAddF32(&accDg[nb + gi], accD[t][r]);
            float* np_ = accNg + (nb + gi) * N_HID + m;
            atomAddF32(np_ + 0,  accN[t][0][r]);
            atomAddF32(np_ + 16, accN[t][1][r]);
            atomAddF32(np_ + 32, accN[t][2][r]);
            atomAddF32(np_ + 48, accN[t][3][r]);
        }
    }
}

// ---------------- Kernel 3: divide + mean over heads (6.4 MB read, trivial)
__global__ __launch_bounds__(256) void finalize_kernel(
    const float* __restrict__ accNg, const float* __restrict__ accDg,
    float* __restrict__ out)
{
    const int idx = blockIdx.x * 256 + threadIdx.x;   // over N_NODES*16
    if (idx >= N_NODES * 16) return;
    const int i = idx >> 4;
    const int d4 = (idx & 15) * 4;
    float sx = 0.f, sy = 0.f, sz = 0.f, sw = 0.f;
    #pragma unroll
    for (int hh = 0; hh < N_HEADS; ++hh) {
        const float4 v = *(const float4*)(accNg + ((size_t)hh * N_NODES + i) * N_HID + d4);
        const float r = 1.0f / accDg[hh * N_NODES + i];
        sx += v.x * r; sy += v.y * r; sz += v.z * r; sw += v.w * r;
    }
    float4 o; o.x = 0.25f * sx; o.y = 0.25f * sy; o.z = 0.25f * sz; o.w = 0.25f * sw;
    *(float4*)(out + (size_t)i * N_HID + d4) = o;
}

extern "C" void kernel_launch(void* const* d_in, const int* in_sizes, int n_in,
                              void* d_out, int out_size, void* d_ws, size_t ws_size,
                              hipStream_t stream)
{
    const float* h   = (const float*)d_in[0];
    const int*   adj = (const int*)d_in[1];
    const float* W   = (const float*)d_in[2];
    const float* a   = (const float*)d_in[3];
    float* out = (float*)d_out;

    // Workspace layout (total ~14.45 MB — well within the round-0-proven footprint):
    char* ws = (char*)d_ws;
    short* htF = (short*)ws;
    size_t off = (size_t)N_HEADS * N_HID * N_NODES * 2;              // 3.15 MB
    float* srcv = (float*)(ws + off);        off += (size_t)N_HEADS * N_NODES * 4;
    unsigned* tE1pk = (unsigned*)(ws + off); off += (size_t)N_HEADS * (N_NODES/2) * 4;
    unsigned* tE2pk = (unsigned*)(ws + off); off += (size_t)N_HEADS * (N_NODES/2) * 4;
    unsigned long long* gmask = (unsigned long long*)(ws + off);
    off += (size_t)JS * N_NODES * 12 * 8;                            // 4.72 MB
    float* accN = (float*)(ws + off);        off += (size_t)N_HEADS * N_NODES * N_HID * 4; // 6.29 MB
    float* accD = (float*)(ws + off);        off += (size_t)N_HEADS * N_NODES * 4;         // contiguous after accN

    prep_kernel<<<PACK_BLOCKS + (N_NODES / 32) * N_HEADS, 256, 0, stream>>>(
        h, W, a, adj, htF, srcv, tE1pk, tE2pk, gmask, accN /* zero base: accN+accD */);
    gat_main_kernel<<<1536, dim3(64, 4), 0, stream>>>(
        (const unsigned*)gmask, htF, srcv, tE1pk, tE2pk, accN, accD);
    finalize_kernel<<<(N_NODES * 16 + 255) / 256, 256, 0, stream>>>(accN, accD, out);
}

// Round 3
// 295.667 us; speedup vs baseline: 1.0287x; 1.0287x over previous
//
#include <hip/hip_runtime.h>
#include <hip/hip_bf16.h>

#define N_NODES 6144
#define IN_F 256
#define N_HEADS 4
#define N_HID 64
#define JS 6                       // j-chunks
#define JLEN (N_NODES / JS)        // 1024
#define NW (JLEN / 32)             // 32 u32 mask words per chunk row
#define SMW 33                     // LDS stride (words) for 32-word mask rows
#define PACK_BLOCKS 768

typedef __attribute__((ext_vector_type(4))) float floatx4;
typedef _Float16 half2_t __attribute__((ext_vector_type(2)));
typedef _Float16 half8_t __attribute__((ext_vector_type(8)));
typedef __attribute__((ext_vector_type(4))) unsigned uint4_t;
typedef short short2v __attribute__((ext_vector_type(2)));

// ---------------- Kernel 1 (fused, parity-interleaved): even blocks pack adj ->
// 64-bit ballot masks (HBM-bound); odd blocks do ht = h @ W fp32 (VALU/LDS-bound).
// Parity interleave => both kinds co-resident from the first scheduling wave, so
// the adj HBM stream hides under the GEMM compute (round-2's [0,768)+[768,1536)
// split serialized them).
// gmask layout (flat, jc-agnostic): u64 word r*96 + c covers j = c*64 + bit.
__global__ __launch_bounds__(256) void prep_kernel(
    const float* __restrict__ h, const float* __restrict__ W,
    const float* __restrict__ a, const int* __restrict__ adj,
    short* __restrict__ htF, float* __restrict__ srcv,
    unsigned* __restrict__ tE1pk, unsigned* __restrict__ tE2pk,
    unsigned long long* __restrict__ gmask)
{
    __shared__ float As[32][34];
    __shared__ float Bs[32][68];
    __shared__ float redS[32][16];
    __shared__ float redT[32][16];
    __shared__ unsigned short eh1[32], eh2[32];

    if ((blockIdx.x & 1) == 0) {
        // ---- adjacency ballot-pack: 192 u64 words per wave, 16-way unrolled
        const int pb = blockIdx.x >> 1;              // [0,768)
        const int lane = threadIdx.x & 63;
        const int wave = threadIdx.x >> 6;
        const int wbase = (pb * 4 + wave) * 192;
        for (int k0 = 0; k0 < 192; k0 += 16) {
            int v[16];
            #pragma unroll
            for (int s = 0; s < 16; ++s) {
                const int widx = wbase + k0 + s;
                const int r = widx / 96, c = widx % 96;     // row, 64-col group
                v[s] = adj[(size_t)r * N_NODES + c * 64 + lane];
            }
            #pragma unroll
            for (int s = 0; s < 16; ++s) {
                const unsigned long long b = __ballot(v[s] > 0);
                const int widx = wbase + k0 + s;
                const int r = widx / 96, c = widx % 96;
                if (lane == 0)
                    gmask[(size_t)r * 96 + c] = b;
            }
        }
        return;
    }

    // ---- ht GEMM (unchanged math)
    const int gbx = blockIdx.x >> 1;                 // [0,768)
    const int head = gbx & 3;
    const int i0 = (gbx >> 2) * 32;
    const int tid = threadIdx.x;
    const int tx = tid & 15, ty = tid >> 4;

    float acc[2][4] = {};

    for (int k0 = 0; k0 < IN_F; k0 += 32) {
        __syncthreads();
        {
            const int m = tid >> 3, kq = tid & 7;
            const float4 v = *(const float4*)(h + (i0 + m) * IN_F + k0 + kq * 4);
            As[kq*4+0][m] = v.x; As[kq*4+1][m] = v.y;
            As[kq*4+2][m] = v.z; As[kq*4+3][m] = v.w;
        }
        #pragma unroll
        for (int it = 0; it < 2; ++it) {
            int l = it * 256 + tid;
            int k = l >> 4, nq = l & 15;
            *(float4*)&Bs[k][nq*4] = *(const float4*)(W + (k0 + k) * 256 + head * 64 + nq * 4);
        }
        __syncthreads();
        #pragma unroll
        for (int kk = 0; kk < 32; ++kk) {
            const float2 av = *(const float2*)&As[kk][ty*2];
            const float4 bv = *(const float4*)&Bs[kk][tx*4];
            const float aa[2] = {av.x, av.y};
            const float bb[4] = {bv.x, bv.y, bv.z, bv.w};
            #pragma unroll
            for (int r = 0; r < 2; ++r)
                #pragma unroll
                for (int c = 0; c < 4; ++c)
                    acc[r][c] = fmaf(aa[r], bb[c], acc[r][c]);
        }
    }

    #pragma unroll
    for (int r = 0; r < 2; ++r)
        #pragma unroll
        for (int c2 = 0; c2 < 4; ++c2) {
            const int d = tx * 4 + c2;
            const int j = i0 + ty * 2 + r;
            const int jt = j >> 5, q = (j >> 3) & 3, u = j & 7;
            const int c = d >> 4, n = d & 15;
            const size_t F = (((((size_t)head * 192 + jt) * 4 + c) * 16 + n) * 4 + q) * 8 + u;
            const _Float16 hv = (_Float16)acc[r][c2];
            htF[F] = *(const short*)&hv;
        }

    float as_[4], at_[4];
    #pragma unroll
    for (int c = 0; c < 4; ++c) {
        as_[c] = a[head * 128 + tx * 4 + c];
        at_[c] = a[head * 128 + 64 + tx * 4 + c];
    }
    #pragma unroll
    for (int r = 0; r < 2; ++r) {
        float ps = 0.f, pt = 0.f;
        #pragma unroll
        for (int c = 0; c < 4; ++c) {
            ps = fmaf(acc[r][c], as_[c], ps);
            pt = fmaf(acc[r][c], at_[c], pt);
        }
        redS[ty*2+r][tx] = ps;
        redT[ty*2+r][tx] = pt;
    }
    __syncthreads();
    if (tid < 64) {
        const int row = tid & 31;
        const float* src = (tid < 32) ? &redS[row][0] : &redT[row][0];
        float s = 0.f;
        #pragma unroll
        for (int x = 0; x < 16; ++x) s += src[x];
        if (tid < 32) {
            srcv[head * N_NODES + i0 + row] = s;
        } else {
            const _Float16 E1 = (_Float16)__expf(s);
            const _Float16 E2 = (_Float16)__expf(0.2f * s);
            eh1[row] = *(const unsigned short*)&E1;
            eh2[row] = *(const unsigned short*)&E2;
        }
    }
    __syncthreads();
    if (tid < 16) {
        const unsigned v1 = (unsigned)eh1[2*tid] | ((unsigned)eh1[2*tid+1] << 16);
        const unsigned v2 = (unsigned)eh2[2*tid] | ((unsigned)eh2[2*tid+1] << 16);
        tE1pk[head * (N_NODES/2) + i0/2 + tid] = v1;
        tE2pk[head * (N_NODES/2) + i0/2 + tid] = v2;
    }
}

// ---------------- Kernel 2: masked softmax + PV. 6 j-chunks x 192 row-blocks of 32
// -> grid 1152 (4.5 blocks/CU offered). Masks pre-packed (4 KB LDS stage); E1/E2
// and htF B-fragments and mask words ALL register-prefetched depth-1. Plain-store
// epilogue to 24-slot partials (no atomics).
__global__ __launch_bounds__(256, 4) void gat_main_kernel(
    const unsigned* __restrict__ gmask32, const short* __restrict__ htF,
    const float* __restrict__ srcv, const unsigned* __restrict__ tE1pk,
    const unsigned* __restrict__ tE2pk,
    float* __restrict__ pnum, float* __restrict__ pden)
{
    __shared__ unsigned smask[32 * SMW];   // 4.2 KB

    const int bid = blockIdx.x;
    const int xcd = bid & 7;
    const int idx = bid >> 3;                     // [0,144)
    const int jc = idx / 24;                      // [0,6)
    const int rb0 = ((idx % 24) * 8 + xcd) * 32;  // 192 row-blocks of 32

    const int lane = threadIdx.x;
    const int head = threadIdx.y;                 // wave = head
    const int m = lane & 15, quad = lane >> 4;
    const int jbase = jc * JLEN;
    const int tid = head * 64 + lane;

    // ---- stage this block's 32x1024-bit mask tile: 32 rows x 32 u32 words
    {
        #pragma unroll
        for (int it = 0; it < 4; ++it) {
            const int f = it * 256 + tid;         // 0..1023
            const int r = f >> 5, w = f & 31;
            smask[r * SMW + w] = gmask32[((size_t)(rb0 + r)) * 192 + jc * 32 + w];
        }
    }
    __syncthreads();

    half2_t e1s[2], e2s[2];
    #pragma unroll
    for (int t = 0; t < 2; ++t) {
        const float sv = srcv[head * N_NODES + rb0 + t * 16 + m];
        const _Float16 a1 = (_Float16)__expf(sv);
        const _Float16 a2 = (_Float16)__expf(0.2f * sv);
        e1s[t] = (half2_t){a1, a1};
        e2s[t] = (half2_t){a2, a2};
    }

    const short* fb = htF + ((size_t)(head * 192 + (jbase >> 5)) * 4) * 512 + (m * 4 + quad) * 8;
    const unsigned* pe1 = tE1pk + head * (N_NODES/2) + (jbase >> 1) + quad * 4;
    const unsigned* pe2 = tE2pk + head * (N_NODES/2) + (jbase >> 1) + quad * 4;

    half8_t bones;
    #pragma unroll
    for (int u = 0; u < 8; ++u) bones[u] = (_Float16)1.0f;

    floatx4 accN[2][4];
    floatx4 accD[2];
    #pragma unroll
    for (int t = 0; t < 2; ++t) {
        accD[t] = (floatx4){0,0,0,0};
        #pragma unroll
        for (int c = 0; c < 4; ++c) accN[t][c] = (floatx4){0,0,0,0};
    }

    // depth-1 prefetch of B-fragments, E words, and mask words
    half8_t bn[4];
    #pragma unroll
    for (int c = 0; c < 4; ++c) bn[c] = *(const half8_t*)(fb + c * 512);
    uint4_t E1n = *(const uint4_t*)pe1;
    uint4_t E2n = *(const uint4_t*)pe2;
    unsigned mwn[2];
    #pragma unroll
    for (int t = 0; t < 2; ++t) mwn[t] = smask[(t * 16 + m) * SMW + 0];

    for (int w = 0; w < NW; ++w) {
        half8_t bc[4];
        #pragma unroll
        for (int c = 0; c < 4; ++c) bc[c] = bn[c];
        const uint4_t E1 = E1n, E2 = E2n;
        const unsigned mw[2] = {mwn[0], mwn[1]};

        const int wn = (w + 1 < NW) ? (w + 1) : w;      // clamped prefetch
        #pragma unroll
        for (int c = 0; c < 4; ++c)
            bn[c] = *(const half8_t*)(fb + (size_t)wn * 2048 + c * 512);
        E1n = *(const uint4_t*)(pe1 + wn * 16);
        E2n = *(const uint4_t*)(pe2 + wn * 16);
        #pragma unroll
        for (int t = 0; t < 2; ++t) mwn[t] = smask[(t * 16 + m) * SMW + wn];

        const unsigned E1a[4] = {E1.x, E1.y, E1.z, E1.w};
        const unsigned E2a[4] = {E2.x, E2.y, E2.z, E2.w};

        #pragma unroll
        for (int t = 0; t < 2; ++t) {
            const unsigned bits = (mw[t] >> (quad * 8)) & 0xffu;
            const short2v tt = __builtin_bit_cast(short2v, bits * 0x10001u);
            uint4_t af_u;
            #pragma unroll
            for (int p = 0; p < 4; ++p) {
                const short2v shl = (p == 0) ? (short2v){15,14} : (p == 1) ? (short2v){13,12}
                                 : (p == 2) ? (short2v){11,10} : (short2v){9,8};
                const short2v k = (tt << shl) >> (short2v){15,15};   // 0xFFFF/0x0000 per half
                const half2_t p1 = __builtin_bit_cast(half2_t, E1a[p]) * e1s[t];
                const half2_t p2 = __builtin_bit_cast(half2_t, E2a[p]) * e2s[t];
                const half2_t mx = __builtin_elementwise_max(p1, p2); // exp(lrelu) = max of exps
                const unsigned r = __builtin_bit_cast(unsigned, mx) & __builtin_bit_cast(unsigned, k);
                if (p == 0) af_u.x = r; else if (p == 1) af_u.y = r;
                else if (p == 2) af_u.z = r; else af_u.w = r;
            }
            const half8_t af = __builtin_bit_cast(half8_t, af_u);
            #pragma unroll
            for (int c = 0; c < 4; ++c)
                accN[t][c] = __builtin_amdgcn_mfma_f32_16x16x32_f16(af, bc[c], accN[t][c], 0, 0, 0);
            accD[t] = __builtin_amdgcn_mfma_f32_16x16x32_f16(af, bones, accD[t], 0, 0, 0);
        }
    }

    const int slot = jc * N_HEADS + head;         // [0,24)
    #pragma unroll
    for (int t = 0; t < 2; ++t) {
        if (m == 0) {
            #pragma unroll
            for (int r = 0; r < 4; ++r)
                pden[slot * N_NODES + rb0 + t * 16 + quad * 4 + r] = accD[t][r];
        }
        #pragma unroll
        for (int r = 0; r < 4; ++r) {
            const int gi = rb0 + t * 16 + quad * 4 + r;
            float* np_ = pnum + ((size_t)slot * N_NODES + gi) * N_HID + m;
            np_[0]  = accN[t][0][r];
            np_[16] = accN[t][1][r];
            np_[32] = accN[t][2][r];
            np_[48] = accN[t][3][r];
        }
    }
}

// ---------------- Kernel 3: reduce 6 j-chunks, divide, mean over heads (float4).
__global__ __launch_bounds__(128) void finalize_kernel(
    const float* __restrict__ pnum, const float* __restrict__ pden,
    float* __restrict__ out)
{
    const int idx = blockIdx.x * 128 + threadIdx.x;   // over N_NODES*16
    if (idx >= N_NODES * 16) return;
    const int i = idx >> 4;
    const int d4 = (idx & 15) * 4;
    float sx = 0.f, sy = 0.f, sz = 0.f, sw = 0.f;
    #pragma unroll
    for (int hh = 0; hh < N_HEADS; ++hh) {
        float nx = 0.f, ny = 0.f, nz = 0.f, nw_ = 0.f, ds = 0.f;
        #pragma unroll
        for (int jc = 0; jc < JS; ++jc) {
            const int slot = jc * N_HEADS + hh;
            const float4 v = *(const float4*)(pnum + ((size_t)slot * N_NODES + i) * N_HID + d4);
            nx += v.x; ny += v.y; nz += v.z; nw_ += v.w;
            ds += pden[slot * N_NODES + i];
        }
        const float r = 1.0f / ds;
        sx += nx * r; sy += ny * r; sz += nz * r; sw += nw_ * r;
    }
    float4 o; o.x = 0.25f * sx; o.y = 0.25f * sy; o.z = 0.25f * sz; o.w = 0.25f * sw;
    *(float4*)(out + (size_t)i * N_HID + d4) = o;
}

extern "C" void kernel_launch(void* const* d_in, const int* in_sizes, int n_in,
                              void* d_out, int out_size, void* d_ws, size_t ws_size,
                              hipStream_t stream)
{
    const float* h   = (const float*)d_in[0];
    const int*   adj = (const int*)d_in[1];
    const float* W   = (const float*)d_in[2];
    const float* a   = (const float*)d_in[3];
    float* out = (float*)d_out;

    // Workspace layout — total 46.4 MB (< round-0-proven 54.5 MB):
    char* ws = (char*)d_ws;
    short* htF = (short*)ws;
    size_t off = (size_t)N_HEADS * N_HID * N_NODES * 2;              // 3.15 MB
    float* srcv = (float*)(ws + off);        off += (size_t)N_HEADS * N_NODES * 4;
    unsigned* tE1pk = (unsigned*)(ws + off); off += (size_t)N_HEADS * (N_NODES/2) * 4;
    unsigned* tE2pk = (unsigned*)(ws + off); off += (size_t)N_HEADS * (N_NODES/2) * 4;
    unsigned long long* gmask = (unsigned long long*)(ws + off);
    off += (size_t)N_NODES * 96 * 8;                                 // 4.72 MB
    float* pnum = (float*)(ws + off);
    off += (size_t)JS * N_HEADS * N_NODES * N_HID * 4;               // 37.75 MB
    float* pden = (float*)(ws + off);                                // 0.59 MB

    prep_kernel<<<2 * PACK_BLOCKS, 256, 0, stream>>>(
        h, W, a, adj, htF, srcv, tE1pk, tE2pk, gmask);
    gat_main_kernel<<<JS * 192, dim3(64, 4), 0, stream>>>(
        (const unsigned*)gmask, htF, srcv, tE1pk, tE2pk, pnum, pden);
    finalize_kernel<<<(N_NODES * 16 + 127) / 128, 128, 0, stream>>>(pnum, pden, out);
}